// Round 1
// baseline (703.583 us; speedup 1.0000x reference)
//
#include <hip/hip_runtime.h>
#include <hip/hip_bf16.h>

typedef unsigned short u16;
typedef __bf16 bf16x8 __attribute__((ext_vector_type(8)));
typedef float f32x4 __attribute__((ext_vector_type(4)));
typedef __attribute__((address_space(1))) void* gp1_t;
typedef __attribute__((address_space(3))) void* lp3_t;

#define D_IN   4096
#define D_OUT  4096
#define M_ROWS 8192   // B*S = 4*2048

// ---- workspace layout (bytes) ----
#define OFF_NORMS  0u          // 4096 f32
#define OFF_QVALS  16384u      // 4 f32: v[204],v[205],v[3890],v[3891]
#define OFF_NBIN   16400u      // 1 f32
#define OFF_MASK   16640u      // 4096 f32 (1.0 = binarized column)
#define OFF_SCALE  33024u      // 4096 f32 (per output row)
#define OFF_PART   49408u      // 32*4096 f32 column-norm partials
#define OFF_XB     573696u     // 8192*4096 bf16 (67108864 B)
#define OFF_WB     67682560u   // 4096*4096 bf16 (33554432 B)
// total ws needed: 101236992 B (~96.6 MB)

static __device__ __forceinline__ u16 f2bf(float f) {
    __hip_bfloat16 h = __float2bfloat16(f);
    u16 u; __builtin_memcpy(&u, &h, 2);
    return u;
}

// 1) column-norm partials: grid (16, 32), block 256. part[by][j] = sum_{128 rows} |W|
__global__ void colnorm_partial(const float* __restrict__ W, float* __restrict__ part) {
    const int j  = blockIdx.x * 256 + threadIdx.x;
    const int r0 = blockIdx.y * 128;
    float s = 0.f;
    #pragma unroll 4
    for (int r = 0; r < 128; ++r) s += fabsf(W[(size_t)(r0 + r) * D_IN + j]);
    part[blockIdx.y * D_IN + j] = s;
}

// 2) reduce partials: grid 16, block 256
__global__ void colnorm_reduce(const float* __restrict__ part, float* __restrict__ norms) {
    const int j = blockIdx.x * 256 + threadIdx.x;
    float s = 0.f;
    #pragma unroll
    for (int p = 0; p < 32; ++p) s += part[p * D_IN + j];
    norms[j] = s;
}

// 3) stable-rank order statistics: grid 16, block 256.
//    jnp.quantile([0.05,0.95]) on n=4096: pos = p*(n-1) -> 204.75 and 3890.25.
__global__ void rank_select(const float* __restrict__ norms, float* __restrict__ qvals) {
    __shared__ float sn[D_IN];
    const int tid = threadIdx.x;
    for (int i = tid; i < D_IN; i += 256) sn[i] = norms[i];
    __syncthreads();
    const int j = blockIdx.x * 256 + tid;
    const float vj = sn[j];
    int r = 0;
    #pragma unroll 8
    for (int i = 0; i < D_IN; ++i) {
        const float vi = sn[i];
        r += (vi < vj) || (vi == vj && i < j);   // stable rank: ties broken by index
    }
    if      (r == 204)  qvals[0] = vj;
    else if (r == 205)  qvals[1] = vj;
    else if (r == 3890) qvals[2] = vj;
    else if (r == 3891) qvals[3] = vj;
}

// 4) mask + n_bin: single block, 1024 threads
__global__ void mask_count(const float* __restrict__ norms, const float* __restrict__ qvals,
                           float* __restrict__ mask, float* __restrict__ nbin) {
    __shared__ float wsum[16];
    const int tid = threadIdx.x;
    const float lower = qvals[0] + 0.75f * (qvals[1] - qvals[0]);
    const float upper = qvals[2] + 0.25f * (qvals[3] - qvals[2]);
    int cnt = 0;
    for (int i = tid; i < D_IN; i += 1024) {
        const float v = norms[i];
        const bool bin = !(v > lower && v < upper);   // binarized = ~middle-band
        mask[i] = bin ? 1.0f : 0.0f;
        cnt += bin ? 1 : 0;
    }
    #pragma unroll
    for (int off = 32; off > 0; off >>= 1) cnt += __shfl_down(cnt, off, 64);
    if ((tid & 63) == 0) wsum[tid >> 6] = (float)cnt;
    __syncthreads();
    if (tid == 0) {
        float s = 0.f;
        #pragma unroll
        for (int w = 0; w < 16; ++w) s += wsum[w];
        *nbin = s;
    }
}

// 5) per-row scale: grid 1024, block 256 (wave per row)
__global__ void row_scale(const float* __restrict__ W, const float* __restrict__ mask,
                          const float* __restrict__ nbin, float* __restrict__ scale) {
    const int wave = threadIdx.x >> 6, lane = threadIdx.x & 63;
    const int o = blockIdx.x * 4 + wave;
    const float* row = W + (size_t)o * D_IN;
    float s = 0.f;
    #pragma unroll 4
    for (int j = lane; j < D_IN; j += 64) s += fabsf(row[j]) * mask[j];
    #pragma unroll
    for (int off = 32; off > 0; off >>= 1) s += __shfl_down(s, off, 64);
    if (lane == 0) scale[o] = s / *nbin;
}

// 6) w_bin bf16: grid 4096 (row per block), block 256, float4 per iter
__global__ void build_wbin(const float* __restrict__ W, const float* __restrict__ mask,
                           const float* __restrict__ scale, u16* __restrict__ wb) {
    const int o = blockIdx.x;
    const float sc = scale[o];
    const float4* row = (const float4*)(W + (size_t)o * D_IN);
    const float4* m4  = (const float4*)mask;
    ushort4* out = (ushort4*)(wb + (size_t)o * D_IN);
    #pragma unroll
    for (int it = 0; it < 4; ++it) {
        const int c = it * 256 + threadIdx.x;
        const float4 w = row[c];
        const float4 mm = m4[c];
        ushort4 r;
        r.x = f2bf(mm.x != 0.f ? w.x * sc : w.x);
        r.y = f2bf(mm.y != 0.f ? w.y * sc : w.y);
        r.z = f2bf(mm.z != 0.f ? w.z * sc : w.z);
        r.w = f2bf(mm.w != 0.f ? w.w * sc : w.w);
        out[c] = r;
    }
}

// 7) x -> bf16: grid 32768, block 256, float4 per thread
__global__ void cast_x(const float* __restrict__ x, u16* __restrict__ xb) {
    const size_t i4 = (size_t)blockIdx.x * 256 + threadIdx.x;
    const float4 v = ((const float4*)x)[i4];
    ushort4 r;
    r.x = f2bf(v.x); r.y = f2bf(v.y); r.z = f2bf(v.z); r.w = f2bf(v.w);
    ((ushort4*)xb)[i4] = r;
}

// 8) GEMM C[m,n] = sum_k A[m,k]*B[n,k] + bias[n]; A,B bf16 row-major, C f32.
//    m97 structure: 128x128 tile, BK=32, 4 waves each 64x64 via 4x4 of 16x16x32 MFMA,
//    global_load_lds width=16 staging (LDS layout = linear chunk order, NO padding).
__global__ __launch_bounds__(256) void gemm_bt(const u16* __restrict__ A, const u16* __restrict__ B,
                                               const float* __restrict__ bias, float* __restrict__ C) {
    __shared__ u16 lA[128 * 32];
    __shared__ u16 lB[128 * 32];
    const int tid  = threadIdx.x;
    const int wave = tid >> 6, lane = tid & 63;
    const int wr = wave >> 1, wc = wave & 1;
    const int m0 = blockIdx.y * 128, n0 = blockIdx.x * 128;

    // staging: chunk c = r*256+tid covers 16B = 8 bf16; row=c>>2, col8=(c&3)*8
    const int srow = tid >> 2;
    const int scol = (tid & 3) * 8;
    const u16* gA0 = A + (size_t)(m0 + srow) * D_IN + scol;
    const u16* gA1 = A + (size_t)(m0 + 64 + srow) * D_IN + scol;
    const u16* gB0 = B + (size_t)(n0 + srow) * D_IN + scol;
    const u16* gB1 = B + (size_t)(n0 + 64 + srow) * D_IN + scol;
    lp3_t lA0 = (lp3_t)(lA + wave * 512);          // wave-uniform base, +lane*16 implied
    lp3_t lA1 = (lp3_t)(lA + 2048 + wave * 512);
    lp3_t lB0 = (lp3_t)(lB + wave * 512);
    lp3_t lB1 = (lp3_t)(lB + 2048 + wave * 512);

    f32x4 acc[4][4] = {};

    const int koff = (lane >> 4) * 8;   // A/B frag: [m|n]=lane&15, k=(lane>>4)*8+j
    const int rsel = lane & 15;

    for (int kt = 0; kt < D_IN; kt += 32) {
        __builtin_amdgcn_global_load_lds((gp1_t)(gA0 + kt), lA0, 16, 0, 0);
        __builtin_amdgcn_global_load_lds((gp1_t)(gA1 + kt), lA1, 16, 0, 0);
        __builtin_amdgcn_global_load_lds((gp1_t)(gB0 + kt), lB0, 16, 0, 0);
        __builtin_amdgcn_global_load_lds((gp1_t)(gB1 + kt), lB1, 16, 0, 0);
        __syncthreads();

        bf16x8 af[4], bfv[4];
        #pragma unroll
        for (int mi = 0; mi < 4; ++mi)
            af[mi] = *(const bf16x8*)(lA + (wr * 64 + mi * 16 + rsel) * 32 + koff);
        #pragma unroll
        for (int ni = 0; ni < 4; ++ni)
            bfv[ni] = *(const bf16x8*)(lB + (wc * 64 + ni * 16 + rsel) * 32 + koff);
        #pragma unroll
        for (int mi = 0; mi < 4; ++mi)
            #pragma unroll
            for (int ni = 0; ni < 4; ++ni)
                acc[mi][ni] = __builtin_amdgcn_mfma_f32_16x16x32_bf16(af[mi], bfv[ni], acc[mi][ni], 0, 0, 0);
        __syncthreads();
    }

    // C/D layout: col = lane&15 (n), row = (lane>>4)*4 + reg (m)
    const int cm = (lane >> 4) * 4;
    const int cn = lane & 15;
    #pragma unroll
    for (int ni = 0; ni < 4; ++ni) {
        const int n = n0 + wc * 64 + ni * 16 + cn;
        const float bv = bias[n];
        #pragma unroll
        for (int mi = 0; mi < 4; ++mi) {
            const int mbase = m0 + wr * 64 + mi * 16 + cm;
            #pragma unroll
            for (int r = 0; r < 4; ++r)
                C[(size_t)(mbase + r) * D_OUT + n] = acc[mi][ni][r] + bv;
        }
    }
}

extern "C" void kernel_launch(void* const* d_in, const int* in_sizes, int n_in,
                              void* d_out, int out_size, void* d_ws, size_t ws_size,
                              hipStream_t stream) {
    const float* x    = (const float*)d_in[0];   // [8192, 4096]
    const float* W    = (const float*)d_in[1];   // [4096, 4096]
    const float* bias = (const float*)d_in[2];   // [4096]
    float* out = (float*)d_out;                  // [8192, 4096]

    char* ws = (char*)d_ws;
    float* norms = (float*)(ws + OFF_NORMS);
    float* qvals = (float*)(ws + OFF_QVALS);
    float* nbin  = (float*)(ws + OFF_NBIN);
    float* mask  = (float*)(ws + OFF_MASK);
    float* scale = (float*)(ws + OFF_SCALE);
    float* part  = (float*)(ws + OFF_PART);
    u16*   xb    = (u16*)(ws + OFF_XB);
    u16*   wb    = (u16*)(ws + OFF_WB);

    colnorm_partial<<<dim3(16, 32), 256, 0, stream>>>(W, part);
    colnorm_reduce<<<16, 256, 0, stream>>>(part, norms);
    rank_select<<<16, 256, 0, stream>>>(norms, qvals);
    mask_count<<<1, 1024, 0, stream>>>(norms, qvals, mask, nbin);
    row_scale<<<1024, 256, 0, stream>>>(W, mask, nbin, scale);
    build_wbin<<<4096, 256, 0, stream>>>(W, mask, scale, wb);
    cast_x<<<32768, 256, 0, stream>>>(x, xb);
    gemm_bt<<<dim3(D_OUT / 128, M_ROWS / 128), 256, 0, stream>>>(xb, wb, bias, out);
}

// Round 2
// 671.271 us; speedup vs baseline: 1.0481x; 1.0481x over previous
//
#include <hip/hip_runtime.h>
#include <hip/hip_bf16.h>

typedef unsigned short u16;
typedef __bf16 bf16x8 __attribute__((ext_vector_type(8)));
typedef float f32x4 __attribute__((ext_vector_type(4)));
typedef __attribute__((address_space(1))) void* gp1_t;
typedef __attribute__((address_space(3))) void* lp3_t;

#define D_IN   4096
#define D_OUT  4096
#define M_ROWS 8192   // B*S = 4*2048

// ---- workspace layout (bytes) ----
#define OFF_NORMS  0u          // 4096 f32 (atomic-accumulated; memset to 0 first)
#define OFF_QVALS  16384u      // 4 f32: v[204],v[205],v[3890],v[3891]
#define OFF_XB     573696u     // 8192*4096 bf16 (67108864 B)
#define OFF_WB     67682560u   // 4096*4096 bf16 (33554432 B)

static __device__ __forceinline__ u16 f2bf(float f) {
    __hip_bfloat16 h = __float2bfloat16(f);
    u16 u; __builtin_memcpy(&u, &h, 2);
    return u;
}

// K1: blocks 0..511 -> column-norm partials (atomicAdd into norms);
//     blocks 512..33279 -> cast x to bf16 (float4 per thread).
__global__ __launch_bounds__(256) void k1_cast_colnorm(const float* __restrict__ x,
                                                       const float* __restrict__ W,
                                                       u16* __restrict__ xb,
                                                       float* __restrict__ norms) {
    const int b = blockIdx.x;
    if (b < 512) {
        const int j  = (b & 15) * 256 + threadIdx.x;
        const int r0 = (b >> 4) * 128;
        float s = 0.f;
        #pragma unroll 4
        for (int r = 0; r < 128; ++r) s += fabsf(W[(size_t)(r0 + r) * D_IN + j]);
        atomicAdd(&norms[j], s);
    } else {
        const size_t i4 = (size_t)(b - 512) * 256 + threadIdx.x;
        const float4 v = ((const float4*)x)[i4];
        ushort4 r;
        r.x = f2bf(v.x); r.y = f2bf(v.y); r.z = f2bf(v.z); r.w = f2bf(v.w);
        ((ushort4*)xb)[i4] = r;
    }
}

// K2: stable-rank order statistics: grid 16, block 256.
//     jnp.quantile([0.05,0.95]) on n=4096: pos = p*(n-1) -> 204.75 and 3890.25.
__global__ void rank_select(const float* __restrict__ norms, float* __restrict__ qvals) {
    __shared__ float sn[D_IN];
    const int tid = threadIdx.x;
    for (int i = tid; i < D_IN; i += 256) sn[i] = norms[i];
    __syncthreads();
    const int j = blockIdx.x * 256 + tid;
    const float vj = sn[j];
    int r = 0;
    #pragma unroll 8
    for (int i = 0; i < D_IN; ++i) {
        const float vi = sn[i];
        r += (vi < vj) || (vi == vj && i < j);   // stable rank: ties broken by index
    }
    if      (r == 204)  qvals[0] = vj;
    else if (r == 205)  qvals[1] = vj;
    else if (r == 3890) qvals[2] = vj;
    else if (r == 3891) qvals[3] = vj;
}

// K3: one block per output row: mask from qvals/norms on the fly, n_bin count,
//     masked row abs-mean, rescale + bf16 cast, single W read.
__global__ __launch_bounds__(256) void k3_scale_wbin(const float* __restrict__ W,
                                                     const float* __restrict__ norms,
                                                     const float* __restrict__ qvals,
                                                     u16* __restrict__ wb) {
    __shared__ float red[8];
    const int o = blockIdx.x, t = threadIdx.x;
    const int wave = t >> 6, lane = t & 63;
    const float lower = qvals[0] + 0.75f * (qvals[1] - qvals[0]);
    const float upper = qvals[2] + 0.25f * (qvals[3] - qvals[2]);
    const float4* row4 = (const float4*)(W + (size_t)o * D_IN);
    const float4* n4   = (const float4*)norms;

    float4 wv[4];
    int binbits[4];
    float cnt = 0.f, sum = 0.f;
    #pragma unroll
    for (int it = 0; it < 4; ++it) {
        const int c = it * 256 + t;
        wv[it] = row4[c];
        const float4 nv = n4[c];
        const bool b0 = !(nv.x > lower && nv.x < upper);
        const bool b1 = !(nv.y > lower && nv.y < upper);
        const bool b2 = !(nv.z > lower && nv.z < upper);
        const bool b3 = !(nv.w > lower && nv.w < upper);
        binbits[it] = (b0 ? 1 : 0) | (b1 ? 2 : 0) | (b2 ? 4 : 0) | (b3 ? 8 : 0);
        cnt += (float)(b0 + b1 + b2 + b3);
        sum += (b0 ? fabsf(wv[it].x) : 0.f) + (b1 ? fabsf(wv[it].y) : 0.f)
             + (b2 ? fabsf(wv[it].z) : 0.f) + (b3 ? fabsf(wv[it].w) : 0.f);
    }
    #pragma unroll
    for (int off = 32; off > 0; off >>= 1) {
        cnt += __shfl_down(cnt, off, 64);
        sum += __shfl_down(sum, off, 64);
    }
    if (lane == 0) { red[wave] = cnt; red[4 + wave] = sum; }
    __syncthreads();
    const float nbin = red[0] + red[1] + red[2] + red[3];
    const float ssum = red[4] + red[5] + red[6] + red[7];
    const float sc = ssum / nbin;

    ushort4* out = (ushort4*)(wb + (size_t)o * D_IN);
    #pragma unroll
    for (int it = 0; it < 4; ++it) {
        const int c = it * 256 + t;
        const int bb = binbits[it];
        ushort4 r;
        r.x = f2bf((bb & 1) ? wv[it].x * sc : wv[it].x);
        r.y = f2bf((bb & 2) ? wv[it].y * sc : wv[it].y);
        r.z = f2bf((bb & 4) ? wv[it].z * sc : wv[it].z);
        r.w = f2bf((bb & 8) ? wv[it].w * sc : wv[it].w);
        out[c] = r;
    }
}

// K4: GEMM C[m,n] = sum_k A[m,k]*B[n,k] + bias[n]; A,B bf16 row-major, C f32.
//     128x128 tile, BK=32, global_load_lds width=16, LDS chunk swizzle:
//     chunk c of row r lives at 16B-slot  r*4 + ((c + (r>>1)) & 3)
//     -> for fixed c, quarter-wave rows spread over all 8 bank groups (2-way = free).
__global__ __launch_bounds__(256) void gemm_bt(const u16* __restrict__ A, const u16* __restrict__ B,
                                               const float* __restrict__ bias, float* __restrict__ C) {
    __shared__ u16 lA[128 * 32];
    __shared__ u16 lB[128 * 32];
    const int tid  = threadIdx.x;
    const int wave = tid >> 6, lane = tid & 63;
    const int wr = wave >> 1, wc = wave & 1;
    const int m0 = blockIdx.y * 128, n0 = blockIdx.x * 128;

    // DMA writer: lane writes slot tid (16B each). Fetch the global chunk that
    // belongs at this slot: local row r = tid>>2, chunk cc = ((tid&3) - (r>>1)) & 3.
    const int r    = tid >> 2;
    const int cc   = ((tid & 3) - ((r >> 1) & 3)) & 3;
    const int scol = cc * 8;
    const u16* gA0 = A + (size_t)(m0 + r) * D_IN + scol;
    const u16* gA1 = A + (size_t)(m0 + 64 + r) * D_IN + scol;
    const u16* gB0 = B + (size_t)(n0 + r) * D_IN + scol;
    const u16* gB1 = B + (size_t)(n0 + 64 + r) * D_IN + scol;
    lp3_t lA0 = (lp3_t)(lA + wave * 512);
    lp3_t lA1 = (lp3_t)(lA + 2048 + wave * 512);
    lp3_t lB0 = (lp3_t)(lB + wave * 512);
    lp3_t lB1 = (lp3_t)(lB + 2048 + wave * 512);

    f32x4 acc[4][4] = {};

    const int cl   = lane >> 4;     // logical chunk (k-quarter) this lane reads
    const int rsel = lane & 15;

    for (int kt = 0; kt < D_IN; kt += 32) {
        __builtin_amdgcn_global_load_lds((gp1_t)(gA0 + kt), lA0, 16, 0, 0);
        __builtin_amdgcn_global_load_lds((gp1_t)(gA1 + kt), lA1, 16, 0, 0);
        __builtin_amdgcn_global_load_lds((gp1_t)(gB0 + kt), lB0, 16, 0, 0);
        __builtin_amdgcn_global_load_lds((gp1_t)(gB1 + kt), lB1, 16, 0, 0);
        __syncthreads();

        bf16x8 af[4], bfv[4];
        #pragma unroll
        for (int mi = 0; mi < 4; ++mi) {
            const int row = wr * 64 + mi * 16 + rsel;
            const int s = row * 4 + ((cl + (row >> 1)) & 3);
            af[mi] = *(const bf16x8*)(lA + s * 8);
        }
        #pragma unroll
        for (int ni = 0; ni < 4; ++ni) {
            const int row = wc * 64 + ni * 16 + rsel;
            const int s = row * 4 + ((cl + (row >> 1)) & 3);
            bfv[ni] = *(const bf16x8*)(lB + s * 8);
        }
        #pragma unroll
        for (int mi = 0; mi < 4; ++mi)
            #pragma unroll
            for (int ni = 0; ni < 4; ++ni)
                acc[mi][ni] = __builtin_amdgcn_mfma_f32_16x16x32_bf16(af[mi], bfv[ni], acc[mi][ni], 0, 0, 0);
        __syncthreads();
    }

    // C/D layout: col = lane&15 (n), row = (lane>>4)*4 + reg (m)
    const int cm = (lane >> 4) * 4;
    const int cn = lane & 15;
    #pragma unroll
    for (int ni = 0; ni < 4; ++ni) {
        const int n = n0 + wc * 64 + ni * 16 + cn;
        const float bv = bias[n];
        #pragma unroll
        for (int mi = 0; mi < 4; ++mi) {
            const int mbase = m0 + wr * 64 + mi * 16 + cm;
            #pragma unroll
            for (int rr = 0; rr < 4; ++rr)
                C[(size_t)(mbase + rr) * D_OUT + n] = acc[mi][ni][rr] + bv;
        }
    }
}

extern "C" void kernel_launch(void* const* d_in, const int* in_sizes, int n_in,
                              void* d_out, int out_size, void* d_ws, size_t ws_size,
                              hipStream_t stream) {
    const float* x    = (const float*)d_in[0];   // [8192, 4096]
    const float* W    = (const float*)d_in[1];   // [4096, 4096]
    const float* bias = (const float*)d_in[2];   // [4096]
    float* out = (float*)d_out;                  // [8192, 4096]

    char* ws = (char*)d_ws;
    float* norms = (float*)(ws + OFF_NORMS);
    float* qvals = (float*)(ws + OFF_QVALS);
    u16*   xb    = (u16*)(ws + OFF_XB);
    u16*   wb    = (u16*)(ws + OFF_WB);

    hipMemsetAsync(norms, 0, D_IN * sizeof(float), stream);
    k1_cast_colnorm<<<512 + 32768, 256, 0, stream>>>(x, W, xb, norms);
    rank_select<<<16, 256, 0, stream>>>(norms, qvals);
    k3_scale_wbin<<<4096, 256, 0, stream>>>(W, norms, qvals, wb);
    gemm_bt<<<dim3(D_OUT / 128, M_ROWS / 128), 256, 0, stream>>>(xb, wb, bias, out);
}